// Round 1
// baseline (546.814 us; speedup 1.0000x reference)
//
#include <hip/hip_runtime.h>
#include <hip/hip_bf16.h>

#define DM 256
#define NHEAD 8
#define DH 32
#define NBATCH 128
#define SQ 384
#define SK 384

typedef __bf16 bf16x4 __attribute__((ext_vector_type(4)));
typedef __bf16 bf16x8 __attribute__((ext_vector_type(8)));
typedef float f32x4 __attribute__((ext_vector_type(4)));

union BF8 { bf16x8 v8; bf16x4 v4[2]; };

__device__ __forceinline__ unsigned short f2bf(float f) {
    union { float fv; unsigned u; } v; v.fv = f;
    unsigned r = v.u + 0x7FFFu + ((v.u >> 16) & 1u);
    return (unsigned short)(r >> 16);
}

// ---------------------------------------------------------------------------
// Dual projection GEMM: A[M,256] fp32  ->  out1 = post1(A@W1), out2 = post2(A@W2)
// W row-major [k=256][n=256]. blockIdx.y in 0..7: y>>2 selects W1/W2 half,
// (y&3)*64 selects 64-col slab. 64x64 output tile per block, 4 waves,
// K staged in 2 chunks of 128 (LDS 2 x 17KB).
// MODE 0: out1 = bf16(q * scale), out2f = sigmoid(x + gb[col])  (fp32 gate)
// MODE 1: out1 = bf16(k),         out2b = bf16(v)
// ---------------------------------------------------------------------------
template<int MODE>
__global__ __launch_bounds__(256)
void proj_dual_kernel(const float* __restrict__ A,
                      const float* __restrict__ W1,
                      const float* __restrict__ W2,
                      const float* __restrict__ gb,
                      unsigned short* __restrict__ out1,
                      unsigned short* __restrict__ out2b,
                      float* __restrict__ out2f)
{
    const int LDA = 136;   // 128 + 8 pad (ushorts) -> 272B rows, bank-spread
    __shared__ unsigned short A_lds[64 * LDA];
    __shared__ unsigned short Wt_lds[64 * LDA];

    const int tid = threadIdx.x;
    const int lane = tid & 63;
    const int w = tid >> 6;          // wave id: row-block
    const int lr = lane & 15, lg = lane >> 4;
    const int m0 = blockIdx.x * 64;
    const int by = blockIdx.y;
    const int half = by >> 2;
    const int n0 = (by & 3) * 64;
    const float* W = half ? W2 : W1;

    const f32x4 zz = {0.f, 0.f, 0.f, 0.f};
    f32x4 acc[4];
#pragma unroll
    for (int i = 0; i < 4; ++i) acc[i] = zz;

#pragma unroll
    for (int kc = 0; kc < 2; ++kc) {
        if (kc) __syncthreads();
        // stage A chunk: 64 rows x 128 k (fp32 -> bf16)
#pragma unroll
        for (int i = 0; i < 8; ++i) {
            int pos = tid + i * 256;           // 2048 float4 slots
            int row = pos >> 5;
            int c4 = (pos & 31) << 2;
            float4 v = *(const float4*)&A[(size_t)(m0 + row) * DM + kc * 128 + c4];
            ushort4 o;
            o.x = f2bf(v.x); o.y = f2bf(v.y); o.z = f2bf(v.z); o.w = f2bf(v.w);
            *(ushort4*)&A_lds[row * LDA + c4] = o;
        }
        // stage W transposed: Wt[n][k] = W[kc*128+k][n0+n]
#pragma unroll
        for (int i = 0; i < 8; ++i) {
            int pos = tid + i * 256;
            int k = pos >> 4;                  // 0..127
            int nq = (pos & 15) << 2;          // 0..60
            float4 v = *(const float4*)&W[(size_t)(kc * 128 + k) * DM + n0 + nq];
            Wt_lds[(nq + 0) * LDA + k] = f2bf(v.x);
            Wt_lds[(nq + 1) * LDA + k] = f2bf(v.y);
            Wt_lds[(nq + 2) * LDA + k] = f2bf(v.z);
            Wt_lds[(nq + 3) * LDA + k] = f2bf(v.w);
        }
        __syncthreads();

#pragma unroll
        for (int ks = 0; ks < 4; ++ks) {
            int k0 = ks * 32;
            BF8 a;
            a.v4[0] = *(const bf16x4*)&A_lds[(w * 16 + lr) * LDA + k0 + 4 * lg];
            a.v4[1] = *(const bf16x4*)&A_lds[(w * 16 + lr) * LDA + k0 + 16 + 4 * lg];
#pragma unroll
            for (int nf = 0; nf < 4; ++nf) {
                BF8 bop;
                bop.v4[0] = *(const bf16x4*)&Wt_lds[(nf * 16 + lr) * LDA + k0 + 4 * lg];
                bop.v4[1] = *(const bf16x4*)&Wt_lds[(nf * 16 + lr) * LDA + k0 + 16 + 4 * lg];
                acc[nf] = __builtin_amdgcn_mfma_f32_16x16x32_bf16(a.v8, bop.v8, acc[nf], 0, 0, 0);
            }
        }
    }

    // epilogue: D layout col = lane&15, row = 4*(lane>>4)+reg
#pragma unroll
    for (int nf = 0; nf < 4; ++nf) {
        int col = n0 + nf * 16 + lr;
#pragma unroll
        for (int r = 0; r < 4; ++r) {
            int row = m0 + w * 16 + 4 * lg + r;
            float val = acc[nf][r];
            size_t idx = (size_t)row * DM + col;
            if (MODE == 0) {
                if (half == 0) out1[idx] = f2bf(val * 0.17677669529663687f);
                else           out2f[idx] = 1.f / (1.f + __expf(-(val + gb[col])));
            } else {
                if (half == 0) out1[idx] = f2bf(val);
                else           out2b[idx] = f2bf(val);
            }
        }
    }
}

// ---------------------------------------------------------------------------
// Attention: one block = (batch b, 64-row q tile), 8 waves = 8 heads.
// K loop in tiles of 64. Online softmax. Bias [B,1,Q,K] read once per block
// (all 8 waves hit the same addresses -> L1). P goes through wave-private LDS
// to reshape D-layout -> A-fragment layout for the PV MFMA.
// Epilogue: /l, *gate, store bf16 gated weighted_avg.
// ---------------------------------------------------------------------------
__global__ __launch_bounds__(512)
void attn_kernel(const unsigned short* __restrict__ Qb,   // [B*SQ, 256] bf16 (pre-scaled)
                 const unsigned short* __restrict__ Kb,   // [B*SK, 256] bf16
                 const unsigned short* __restrict__ Vb,   // [B*SK, 256] bf16
                 const float* __restrict__ gate,          // [B*SQ, 256] fp32
                 const float* __restrict__ bias,          // [B, SQ, SK] fp32
                 const float* __restrict__ nbias,         // [H, SQ, SK] fp32
                 unsigned short* __restrict__ wavg)       // [B*SQ, 256] bf16
{
    extern __shared__ unsigned short smem[];
    const int LQ = 264;                       // 256 + 8 pad
    unsigned short* Q_lds  = smem;            // [64][264]
    unsigned short* K_lds  = Q_lds + 64 * LQ; // [64][264]
    unsigned short* VT_lds = K_lds + 64 * LQ; // [8][32][72]  VT[h][c][kk]
    unsigned short* P_lds  = VT_lds + 8 * 32 * 72; // [8 waves][16][72]

    const int tid = threadIdx.x;
    const int wv = tid >> 6;                  // wave = head
    const int lane = tid & 63;
    const int lr = lane & 15, lg = lane >> 4;
    const int b = blockIdx.x / 6;
    const int q0 = (blockIdx.x % 6) * 64;
    const int h = wv;

    // stage Q tile 64x256
#pragma unroll
    for (int i = 0; i < 8; ++i) {
        int pos = tid + i * 512;              // 4096 ushort4 slots
        int row = pos >> 6;
        int c4 = (pos & 63) << 2;
        *(ushort4*)&Q_lds[row * LQ + c4] =
            *(const ushort4*)&Qb[(size_t)(b * SQ + q0 + row) * DM + c4];
    }
    __syncthreads();

    // preload Q fragments (fixed across K loop)
    BF8 qf[4];
#pragma unroll
    for (int rb = 0; rb < 4; ++rb) {
        qf[rb].v4[0] = *(const bf16x4*)&Q_lds[(rb * 16 + lr) * LQ + h * DH + 4 * lg];
        qf[rb].v4[1] = *(const bf16x4*)&Q_lds[(rb * 16 + lr) * LQ + h * DH + 16 + 4 * lg];
    }

    const f32x4 zz = {0.f, 0.f, 0.f, 0.f};
    f32x4 Oacc[4][2];
    float mrow[4][4], lrow[4][4];
#pragma unroll
    for (int rb = 0; rb < 4; ++rb) {
        Oacc[rb][0] = zz; Oacc[rb][1] = zz;
#pragma unroll
        for (int r = 0; r < 4; ++r) { mrow[rb][r] = -1e30f; lrow[rb][r] = 0.f; }
    }

    const float* biasrow = bias + (size_t)b * SQ * SK;
    const float* nbrow = nbias + (size_t)h * SQ * SK;

    for (int kb = 0; kb < 6; ++kb) {
        const int k0 = kb * 64;
        __syncthreads();   // previous tile fully consumed
        // stage K tile 64x256
#pragma unroll
        for (int i = 0; i < 8; ++i) {
            int pos = tid + i * 512;
            int row = pos >> 6;
            int c4 = (pos & 63) << 2;
            *(ushort4*)&K_lds[row * LQ + c4] =
                *(const ushort4*)&Kb[(size_t)(b * SK + k0 + row) * DM + c4];
        }
        // stage V transposed per head: VT[h][c][kk] = V[b, k0+kk, h*32+c]
#pragma unroll
        for (int i = 0; i < 8; ++i) {
            int pos = tid + i * 512;
            int kk = pos >> 6;
            int col = (pos & 63) << 2;
            ushort4 vv = *(const ushort4*)&Vb[(size_t)(b * SK + k0 + kk) * DM + col];
            int hh = col >> 5;
            int c = col & 31;
            VT_lds[(hh * 32 + c + 0) * 72 + kk] = vv.x;
            VT_lds[(hh * 32 + c + 1) * 72 + kk] = vv.y;
            VT_lds[(hh * 32 + c + 2) * 72 + kk] = vv.z;
            VT_lds[(hh * 32 + c + 3) * 72 + kk] = vv.w;
        }
        __syncthreads();

        // K fragments (B operand for S = Q @ K^T): n = local k index
        BF8 kf[4];
#pragma unroll
        for (int nf = 0; nf < 4; ++nf) {
            kf[nf].v4[0] = *(const bf16x4*)&K_lds[(nf * 16 + lr) * LQ + h * DH + 4 * lg];
            kf[nf].v4[1] = *(const bf16x4*)&K_lds[(nf * 16 + lr) * LQ + h * DH + 16 + 4 * lg];
        }
        // V fragments (B operand for P @ V): [kchunk][cfrag]
        BF8 vb[2][2];
#pragma unroll
        for (int kc = 0; kc < 2; ++kc)
#pragma unroll
            for (int cf = 0; cf < 2; ++cf) {
                vb[kc][cf].v4[0] = *(const bf16x4*)&VT_lds[(h * 32 + cf * 16 + lr) * 72 + kc * 32 + 4 * lg];
                vb[kc][cf].v4[1] = *(const bf16x4*)&VT_lds[(h * 32 + cf * 16 + lr) * 72 + kc * 32 + 16 + 4 * lg];
            }

#pragma unroll
        for (int rb = 0; rb < 4; ++rb) {
            f32x4 s[4];
#pragma unroll
            for (int nf = 0; nf < 4; ++nf)
                s[nf] = __builtin_amdgcn_mfma_f32_16x16x32_bf16(qf[rb].v8, kf[nf].v8, zz, 0, 0, 0);
            // add pair bias + per-head bias (fp32, exact)
#pragma unroll
            for (int nf = 0; nf < 4; ++nf) {
                int kcol = k0 + nf * 16 + lr;
#pragma unroll
                for (int r = 0; r < 4; ++r) {
                    int qrow = q0 + rb * 16 + 4 * lg + r;
                    s[nf][r] += biasrow[(size_t)qrow * SK + kcol] + nbrow[(size_t)qrow * SK + kcol];
                }
            }
            // online softmax (rows live in 16-lane groups)
#pragma unroll
            for (int r = 0; r < 4; ++r) {
                float mx = fmaxf(fmaxf(s[0][r], s[1][r]), fmaxf(s[2][r], s[3][r]));
#pragma unroll
                for (int off = 8; off; off >>= 1) mx = fmaxf(mx, __shfl_xor(mx, off, 64));
                float mold = mrow[rb][r];
                float mnew = fmaxf(mold, mx);
                float corr = __expf(mold - mnew);
                mrow[rb][r] = mnew;
                float ps = 0.f;
#pragma unroll
                for (int nf = 0; nf < 4; ++nf) {
                    float p = __expf(s[nf][r] - mnew);
                    s[nf][r] = p;
                    ps += p;
                }
#pragma unroll
                for (int off = 8; off; off >>= 1) ps += __shfl_xor(ps, off, 64);
                lrow[rb][r] = lrow[rb][r] * corr + ps;
                Oacc[rb][0][r] *= corr;
                Oacc[rb][1][r] *= corr;
                // spill P (D layout) to wave-private LDS as bf16
#pragma unroll
                for (int nf = 0; nf < 4; ++nf)
                    P_lds[(wv * 16 + 4 * lg + r) * 72 + nf * 16 + lr] = f2bf(s[nf][r]);
            }
            // PV: A = P (re-read in A-fragment layout), B = V^T frags
#pragma unroll
            for (int kc = 0; kc < 2; ++kc) {
                BF8 pa;
                pa.v4[0] = *(const bf16x4*)&P_lds[(wv * 16 + lr) * 72 + kc * 32 + 4 * lg];
                pa.v4[1] = *(const bf16x4*)&P_lds[(wv * 16 + lr) * 72 + kc * 32 + 16 + 4 * lg];
#pragma unroll
                for (int cf = 0; cf < 2; ++cf)
                    Oacc[rb][cf] = __builtin_amdgcn_mfma_f32_16x16x32_bf16(pa.v8, vb[kc][cf].v8, Oacc[rb][cf], 0, 0, 0);
            }
        }
    }

    // epilogue: /l, * gate, store bf16
#pragma unroll
    for (int rb = 0; rb < 4; ++rb)
#pragma unroll
        for (int cf = 0; cf < 2; ++cf)
#pragma unroll
            for (int r = 0; r < 4; ++r) {
                int qrow = q0 + rb * 16 + 4 * lg + r;
                int col = h * DH + cf * 16 + lr;
                size_t idx = (size_t)(b * SQ + qrow) * DM + col;
                float val = Oacc[rb][cf][r] / lrow[rb][r];
                val *= gate[idx];
                wavg[idx] = f2bf(val);
            }
}

// ---------------------------------------------------------------------------
// Output projection: out[M,256] = wavg(bf16)[M,256] @ o_w[256,256] + o_bias
// ---------------------------------------------------------------------------
__global__ __launch_bounds__(256)
void out_proj_kernel(const unsigned short* __restrict__ Abf,
                     const float* __restrict__ W,
                     const float* __restrict__ ob,
                     float* __restrict__ out)
{
    const int LDA = 136;
    __shared__ unsigned short A_lds[64 * LDA];
    __shared__ unsigned short Wt_lds[64 * LDA];

    const int tid = threadIdx.x;
    const int lane = tid & 63;
    const int w = tid >> 6;
    const int lr = lane & 15, lg = lane >> 4;
    const int m0 = blockIdx.x * 64;
    const int n0 = blockIdx.y * 64;

    const f32x4 zz = {0.f, 0.f, 0.f, 0.f};
    f32x4 acc[4];
#pragma unroll
    for (int i = 0; i < 4; ++i) acc[i] = zz;

#pragma unroll
    for (int kc = 0; kc < 2; ++kc) {
        if (kc) __syncthreads();
#pragma unroll
        for (int i = 0; i < 8; ++i) {
            int pos = tid + i * 256;
            int row = pos >> 5;
            int c4 = (pos & 31) << 2;
            *(ushort4*)&A_lds[row * LDA + c4] =
                *(const ushort4*)&Abf[(size_t)(m0 + row) * DM + kc * 128 + c4];
        }
#pragma unroll
        for (int i = 0; i < 8; ++i) {
            int pos = tid + i * 256;
            int k = pos >> 4;
            int nq = (pos & 15) << 2;
            float4 v = *(const float4*)&W[(size_t)(kc * 128 + k) * DM + n0 + nq];
            Wt_lds[(nq + 0) * LDA + k] = f2bf(v.x);
            Wt_lds[(nq + 1) * LDA + k] = f2bf(v.y);
            Wt_lds[(nq + 2) * LDA + k] = f2bf(v.z);
            Wt_lds[(nq + 3) * LDA + k] = f2bf(v.w);
        }
        __syncthreads();
#pragma unroll
        for (int ks = 0; ks < 4; ++ks) {
            int k0 = ks * 32;
            BF8 a;
            a.v4[0] = *(const bf16x4*)&A_lds[(w * 16 + lr) * LDA + k0 + 4 * lg];
            a.v4[1] = *(const bf16x4*)&A_lds[(w * 16 + lr) * LDA + k0 + 16 + 4 * lg];
#pragma unroll
            for (int nf = 0; nf < 4; ++nf) {
                BF8 bop;
                bop.v4[0] = *(const bf16x4*)&Wt_lds[(nf * 16 + lr) * LDA + k0 + 4 * lg];
                bop.v4[1] = *(const bf16x4*)&Wt_lds[(nf * 16 + lr) * LDA + k0 + 16 + 4 * lg];
                acc[nf] = __builtin_amdgcn_mfma_f32_16x16x32_bf16(a.v8, bop.v8, acc[nf], 0, 0, 0);
            }
        }
    }

#pragma unroll
    for (int nf = 0; nf < 4; ++nf) {
        int col = n0 + nf * 16 + lr;
#pragma unroll
        for (int r = 0; r < 4; ++r) {
            int row = m0 + w * 16 + 4 * lg + r;
            out[(size_t)row * DM + col] = acc[nf][r] + ob[col];
        }
    }
}

// ---------------------------------------------------------------------------
extern "C" void kernel_launch(void* const* d_in, const int* in_sizes, int n_in,
                              void* d_out, int out_size, void* d_ws, size_t ws_size,
                              hipStream_t stream) {
    const float* q_data = (const float*)d_in[0];
    const float* m_data = (const float*)d_in[1];
    const float* bias   = (const float*)d_in[2];
    const float* nbias  = (const float*)d_in[3];
    const float* q_w    = (const float*)d_in[4];
    const float* k_w    = (const float*)d_in[5];
    const float* v_w    = (const float*)d_in[6];
    const float* o_w    = (const float*)d_in[7];
    const float* o_b    = (const float*)d_in[8];
    const float* g_w    = (const float*)d_in[9];
    const float* g_b    = (const float*)d_in[10];
    float* out = (float*)d_out;

    const size_t M = (size_t)NBATCH * SQ;           // 49152
    const size_t BF_BYTES = M * DM * 2;             // 25165824
    char* ws = (char*)d_ws;
    unsigned short* qb   = (unsigned short*)(ws);
    unsigned short* kb   = (unsigned short*)(ws + BF_BYTES);
    unsigned short* vb   = (unsigned short*)(ws + 2 * BF_BYTES);
    float*          gate = (float*)(ws + 3 * BF_BYTES);
    unsigned short* wavg = (unsigned short*)(ws + 3 * BF_BYTES + M * DM * 4);

    dim3 g1(768, 8);
    proj_dual_kernel<0><<<g1, 256, 0, stream>>>(q_data, q_w, g_w, g_b, qb, nullptr, gate);
    proj_dual_kernel<1><<<g1, 256, 0, stream>>>(m_data, k_w, v_w, nullptr, kb, vb, nullptr);

    const int ATTN_SMEM = (64 * 264 + 64 * 264 + 8 * 32 * 72 + 8 * 16 * 72) * 2; // 122880 B
    hipFuncSetAttribute((const void*)attn_kernel,
                        hipFuncAttributeMaxDynamicSharedMemorySize, ATTN_SMEM);
    attn_kernel<<<768, 512, ATTN_SMEM, stream>>>(qb, kb, vb, gate, bias, nbias, wavg);

    out_proj_kernel<<<dim3(768, 4), 256, 0, stream>>>(wavg, o_w, o_b, out);
}

// Round 3
// 413.860 us; speedup vs baseline: 1.3213x; 1.3213x over previous
//
#include <hip/hip_runtime.h>
#include <hip/hip_bf16.h>

#define DM 256
#define NB 128
#define SQ 384
#define SK 384

typedef __bf16 bf16x4 __attribute__((ext_vector_type(4)));
typedef __bf16 bf16x8 __attribute__((ext_vector_type(8)));
typedef float f32x4 __attribute__((ext_vector_type(4)));
typedef unsigned short u16;
typedef unsigned int u32;

union BF8 { bf16x8 v8; bf16x4 v4[2]; uint2 u2[2]; };

__device__ __forceinline__ u16 f2bf(float f) {
    union { float fv; u32 u; } v; v.fv = f;
    u32 r = v.u + 0x7FFFu + ((v.u >> 16) & 1u);
    return (u16)(r >> 16);
}
__device__ __forceinline__ float bf2f(u16 u) {
    union { u32 v; float f; } x; x.v = ((u32)u) << 16; return x.f;
}
__device__ __forceinline__ uint2 pack4(float a, float b, float c, float d) {
    uint2 r;
    r.x = (u32)f2bf(a) | ((u32)f2bf(b) << 16);
    r.y = (u32)f2bf(c) | ((u32)f2bf(d) << 16);
    return r;
}

// ---------------------------------------------------------------------------
// prep_w: W[k][n] fp32 -> Wt[n][k] bf16 (scale folded for q_w). 5 matrices.
// ---------------------------------------------------------------------------
__global__ __launch_bounds__(256)
void prep_w(const float* __restrict__ q_w, const float* __restrict__ k_w,
            const float* __restrict__ v_w, const float* __restrict__ g_w,
            const float* __restrict__ o_w, u16* __restrict__ wt)
{
    __shared__ float t[64][65];
    const int mat = blockIdx.z;
    const float* src = mat == 0 ? q_w : mat == 1 ? k_w : mat == 2 ? v_w : mat == 3 ? g_w : o_w;
    const float scale = (mat == 0) ? 0.17677669529663687f : 1.0f;
    const int k0 = blockIdx.x * 64, n0 = blockIdx.y * 64;
    const int tid = threadIdx.x;
#pragma unroll
    for (int i = 0; i < 4; ++i) {
        int pos = tid + i * 256;
        int r = pos >> 4, c4 = (pos & 15) * 4;
        f32x4 v = *(const f32x4*)&src[(size_t)(k0 + r) * DM + n0 + c4];
        t[r][c4 + 0] = v[0]; t[r][c4 + 1] = v[1]; t[r][c4 + 2] = v[2]; t[r][c4 + 3] = v[3];
    }
    __syncthreads();
    const int nr = tid >> 2, kq = (tid & 3) * 16;
    u16* dst = wt + (size_t)mat * DM * DM + (size_t)(n0 + nr) * DM + k0 + kq;
#pragma unroll
    for (int j = 0; j < 16; j += 4) {
        uint2 p = pack4(t[kq + j][nr] * scale, t[kq + j + 1][nr] * scale,
                        t[kq + j + 2][nr] * scale, t[kq + j + 3][nr] * scale);
        *(uint2*)&dst[j] = p;
    }
}

// ---------------------------------------------------------------------------
// proj_kernel: out = A[M,256] @ W[256,256] (+epilogue). A-frags in registers
// (A read once from HBM), Wt slabs staged in swizzled LDS.
// MODE 0: A=q_data fp32; sl<4: qb=bf16(q*scale fold), sl>=4: gate=bf16 sigmoid
// MODE 1: A=m_data fp32; sl<4: kb natural, sl>=4: v -> vT[b][c][kk] transposed
// MODE 2: A=wavg bf16;   4 slabs: out fp32 + o_bias
// ---------------------------------------------------------------------------
template<int MODE>
__global__ __launch_bounds__(256)
void proj_kernel(const float* __restrict__ Af, const u16* __restrict__ Abf,
                 const u16* __restrict__ Wt1, const u16* __restrict__ Wt2,
                 const float* __restrict__ gb, const float* __restrict__ ob,
                 u16* __restrict__ out1, u16* __restrict__ gate,
                 u16* __restrict__ vT, float* __restrict__ outf)
{
    __shared__ u16 Wlds[64 * 256];   // [n 64][k 256 permuted] XOR-swizzled
    const int tid = threadIdx.x, lane = tid & 63, w = tid >> 6;
    const int lr = lane & 15, lg = lane >> 4;
    const int m0 = blockIdx.x * 64;

    // A fragments: af[ks] covers k = ks*32 + {4lg+j, 16+4lg+j}, row m0+w*16+lr
    BF8 af[8];
    if (MODE <= 1) {
        const float* arow = Af + (size_t)(m0 + w * 16 + lr) * DM + 4 * lg;
#pragma unroll
        for (int ks = 0; ks < 8; ++ks) {
            f32x4 v0 = *(const f32x4*)&arow[ks * 32];
            f32x4 v1 = *(const f32x4*)&arow[ks * 32 + 16];
            af[ks].u2[0] = pack4(v0[0], v0[1], v0[2], v0[3]);
            af[ks].u2[1] = pack4(v1[0], v1[1], v1[2], v1[3]);
        }
    } else {
        const u16* arow = Abf + (size_t)(m0 + w * 16 + lr) * DM + 4 * lg;
#pragma unroll
        for (int ks = 0; ks < 8; ++ks) {
            af[ks].u2[0] = *(const uint2*)&arow[ks * 32];
            af[ks].u2[1] = *(const uint2*)&arow[ks * 32 + 16];
        }
    }

    const int NSLAB = (MODE == 2) ? 4 : 8;
    for (int sl = 0; sl < NSLAB; ++sl) {
        const u16* Wsrc = (sl < 4) ? Wt1 : Wt2;
        const int n0 = (sl & 3) * 64;
        if (sl) __syncthreads();
        // stage Wt slab: 64 n-rows x 256 k, permuted-contiguous + XOR swizzle
        // 64 rows x 32 chunks of 8 u16 = 2048 chunks; 256 thr x 8 iters.
#pragma unroll
        for (int i = 0; i < 8; ++i) {
            int pos = tid + i * 256;
            int nr = pos >> 5, c8 = (pos & 31) * 8;
            uint4 gv = *(const uint4*)&Wsrc[(size_t)(n0 + nr) * DM + c8];
            int within = c8 & 31;
            int pa2 = (c8 >> 5) * 64 + ((within >> 3) & 1) * 32 + (within >> 4) * 8;
            int sw = (nr & 7) << 4;
            char* rb_ = (char*)Wlds + nr * 512;
            *(uint2*)(rb_ + (pa2 ^ sw)) = make_uint2(gv.x, gv.y);
            *(uint2*)(rb_ + ((pa2 + 16) ^ sw)) = make_uint2(gv.z, gv.w);
        }
        __syncthreads();

        f32x4 acc[4];
#pragma unroll
        for (int nf = 0; nf < 4; ++nf) acc[nf] = (f32x4){0.f, 0.f, 0.f, 0.f};
#pragma unroll
        for (int ks = 0; ks < 8; ++ks) {
#pragma unroll
            for (int nf = 0; nf < 4; ++nf) {
                int row = nf * 16 + lr;
                bf16x8 bfr = *(const bf16x8*)((char*)Wlds + row * 512 +
                                              ((ks * 64 + lg * 16) ^ ((row & 7) << 4)));
                acc[nf] = __builtin_amdgcn_mfma_f32_16x16x32_bf16(af[ks].v8, bfr, acc[nf], 0, 0, 0);
            }
        }

        // epilogue: D row = m0+w*16+4lg+r, col = n0+nf*16+lr
#pragma unroll
        for (int nf = 0; nf < 4; ++nf) {
            int n = n0 + nf * 16 + lr;
            int gn = (sl & 3) * 64 + nf * 16 + lr;
            if (MODE == 0) {
                if (sl < 4) {
#pragma unroll
                    for (int r = 0; r < 4; ++r)
                        out1[(size_t)(m0 + w * 16 + 4 * lg + r) * DM + n] = f2bf(acc[nf][r]);
                } else {
                    float gbv = gb[gn];
#pragma unroll
                    for (int r = 0; r < 4; ++r)
                        gate[(size_t)(m0 + w * 16 + 4 * lg + r) * DM + gn] =
                            f2bf(1.f / (1.f + __expf(-(acc[nf][r] + gbv))));
                }
            } else if (MODE == 1) {
                if (sl < 4) {
#pragma unroll
                    for (int r = 0; r < 4; ++r)
                        out1[(size_t)(m0 + w * 16 + 4 * lg + r) * DM + n] = f2bf(acc[nf][r]);
                } else {
                    int bb = m0 / SQ;
                    int kkl = m0 - bb * SQ + w * 16 + 4 * lg;
                    *(uint2*)&vT[(size_t)(bb * DM + gn) * SK + kkl] =
                        pack4(acc[nf][0], acc[nf][1], acc[nf][2], acc[nf][3]);
                }
            } else {
                float obv = ob[n];
#pragma unroll
                for (int r = 0; r < 4; ++r)
                    outf[(size_t)(m0 + w * 16 + 4 * lg + r) * DM + n] = acc[nf][r] + obv;
            }
        }
    }
}

// ---------------------------------------------------------------------------
// attn: block = (b, q-tile 64, head-group of 4). wave = head. S^T formulation:
// S^T = mfma(K_frag, Q_frag) -> D cols = q, rows = k. bias as float4 vector
// adds; softmax = 16 in-reg + 2 shfl; P^T regs feed PV directly (no P LDS).
// O^T = mfma(VT_frag, P^T). K/VT tiles: permuted-contig + XOR swizzle.
// ---------------------------------------------------------------------------
__global__ __launch_bounds__(256, 3)
void attn_kernel(const u16* __restrict__ Qb, const u16* __restrict__ Kb,
                 const u16* __restrict__ vT, const u16* __restrict__ gateb,
                 const float* __restrict__ bias, const float* __restrict__ nbias,
                 u16* __restrict__ wavg)
{
    __shared__ u16 Klds[64 * 128];   // [krow][c 128 permuted]  row stride 256B
    __shared__ u16 Vlds[128 * 64];   // [hl*32+c][kk 64 permuted] row stride 128B
    const int tid = threadIdx.x, lane = tid & 63, hl = tid >> 6;
    const int lr = lane & 15, lg = lane >> 4;
    const int b = blockIdx.x / 6, q0 = (blockIdx.x % 6) * 64;
    const int hg = blockIdx.y, h = hg * 4 + hl;

    // Q fragments (B-operand): q = q0+nf*16+lr, c = h*32 + {4lg+j, 16+4lg+j}
    BF8 qf[4];
    {
        const u16* qp = Qb + (size_t)(b * SQ + q0 + lr) * DM + h * 32 + 4 * lg;
#pragma unroll
        for (int nf = 0; nf < 4; ++nf) {
            qf[nf].u2[0] = *(const uint2*)&qp[nf * 16 * DM];
            qf[nf].u2[1] = *(const uint2*)&qp[nf * 16 * DM + 16];
        }
    }

    float m[4], l[4];
    f32x4 Oacc[2][4];
#pragma unroll
    for (int nf = 0; nf < 4; ++nf) {
        m[nf] = -1e30f; l[nf] = 0.f;
        Oacc[0][nf] = (f32x4){0.f, 0.f, 0.f, 0.f};
        Oacc[1][nf] = (f32x4){0.f, 0.f, 0.f, 0.f};
    }

    for (int kb = 0; kb < 6; ++kb) {
        const int k0 = kb * 64;
        __syncthreads();
        // stage K tile: 64 rows x 128 cols (head-group slice)
#pragma unroll
        for (int i = 0; i < 4; ++i) {
            int pos = tid + i * 256;
            int row = pos >> 4, c8 = (pos & 15) * 8;
            uint4 gv = *(const uint4*)&Kb[(size_t)(b * SK + k0 + row) * DM + hg * 128 + c8];
            int within = c8 & 31;
            int pa2 = (c8 >> 5) * 64 + ((within >> 3) & 1) * 32 + (within >> 4) * 8;
            int sw = (row & 7) << 4;
            char* rb_ = (char*)Klds + row * 256;
            *(uint2*)(rb_ + (pa2 ^ sw)) = make_uint2(gv.x, gv.y);
            *(uint2*)(rb_ + ((pa2 + 16) ^ sw)) = make_uint2(gv.z, gv.w);
        }
        // stage VT tile: 128 rows (c) x 64 kk
#pragma unroll
        for (int i = 0; i < 4; ++i) {
            int pos = tid + i * 256;
            int row = pos >> 3, kk8 = (pos & 7) * 8;
            uint4 gv = *(const uint4*)&vT[(size_t)(b * DM + hg * 128 + row) * SK + k0 + kk8];
            int within = kk8 & 31;
            int pa2 = (kk8 >> 5) * 64 + ((within >> 3) & 1) * 32 + (within >> 4) * 8;
            int sw = (row & 7) << 4;
            char* rb_ = (char*)Vlds + row * 128;
            *(uint2*)(rb_ + (pa2 ^ sw)) = make_uint2(gv.x, gv.y);
            *(uint2*)(rb_ + ((pa2 + 16) ^ sw)) = make_uint2(gv.z, gv.w);
        }
        __syncthreads();

        // S^T = K @ Q^T  (D: row = k-local, col = q-local)
        f32x4 st[4][4];
#pragma unroll
        for (int rb = 0; rb < 4; ++rb) {
            int row = rb * 16 + lr;
            bf16x8 kf = *(const bf16x8*)((char*)Klds + row * 256 +
                                         ((hl * 64 + lg * 16) ^ ((lr & 7) << 4)));
#pragma unroll
            for (int nf = 0; nf < 4; ++nf)
                st[rb][nf] = __builtin_amdgcn_mfma_f32_16x16x32_bf16(
                    kf, qf[nf].v8, (f32x4){0.f, 0.f, 0.f, 0.f}, 0, 0, 0);
        }
        // bias + nbias: float4 per (rb,nf)
#pragma unroll
        for (int nf = 0; nf < 4; ++nf) {
            int qrow = q0 + nf * 16 + lr;
            const float* bp = bias + (size_t)(b * SQ + qrow) * SK + k0 + 4 * lg;
            const float* np = nbias + (size_t)(h * SQ + qrow) * SK + k0 + 4 * lg;
#pragma unroll
            for (int rb = 0; rb < 4; ++rb) {
                f32x4 b4 = *(const f32x4*)&bp[rb * 16];
                f32x4 n4 = *(const f32x4*)&np[rb * 16];
                st[rb][nf] += b4 + n4;
            }
        }
        // online softmax per q-column group nf
        BF8 pv[2][4];
#pragma unroll
        for (int nf = 0; nf < 4; ++nf) {
            float mx = st[0][nf][0];
#pragma unroll
            for (int rb = 0; rb < 4; ++rb)
#pragma unroll
                for (int r = 0; r < 4; ++r) mx = fmaxf(mx, st[rb][nf][r]);
            mx = fmaxf(mx, __shfl_xor(mx, 16, 64));
            mx = fmaxf(mx, __shfl_xor(mx, 32, 64));
            float mn = fmaxf(m[nf], mx);
            float corr = __expf(m[nf] - mn);
            m[nf] = mn;
            float ps = 0.f;
#pragma unroll
            for (int rb = 0; rb < 4; ++rb) {
                float p0 = __expf(st[rb][nf][0] - mn);
                float p1 = __expf(st[rb][nf][1] - mn);
                float p2 = __expf(st[rb][nf][2] - mn);
                float p3 = __expf(st[rb][nf][3] - mn);
                ps += (p0 + p1) + (p2 + p3);
                pv[rb >> 1][nf].u2[rb & 1] = pack4(p0, p1, p2, p3);
            }
            ps += __shfl_xor(ps, 16, 64);
            ps += __shfl_xor(ps, 32, 64);
            l[nf] = l[nf] * corr + ps;
            Oacc[0][nf] *= corr;
            Oacc[1][nf] *= corr;
        }
        // O^T += V^T @ P^T
#pragma unroll
        for (int kc = 0; kc < 2; ++kc) {
#pragma unroll
            for (int cf = 0; cf < 2; ++cf) {
                int row = hl * 32 + cf * 16 + lr;
                bf16x8 vf = *(const bf16x8*)((char*)Vlds + row * 128 +
                                             ((kc * 64 + lg * 16) ^ ((lr & 7) << 4)));
#pragma unroll
                for (int nf = 0; nf < 4; ++nf)
                    Oacc[cf][nf] = __builtin_amdgcn_mfma_f32_16x16x32_bf16(
                        vf, pv[kc][nf].v8, Oacc[cf][nf], 0, 0, 0);
            }
        }
    }

    // epilogue: O^T D-layout: row = c-local = cf*16+4lg+r, col = q = nf*16+lr
#pragma unroll
    for (int nf = 0; nf < 4; ++nf) {
        float rl = 1.0f / l[nf];
        size_t qrow = (size_t)(b * SQ + q0 + nf * 16 + lr);
#pragma unroll
        for (int cf = 0; cf < 2; ++cf) {
            size_t idx = qrow * DM + h * 32 + cf * 16 + 4 * lg;
            uint2 g2 = *(const uint2*)&gateb[idx];
            float g0 = bf2f((u16)(g2.x & 0xffff)), g1 = bf2f((u16)(g2.x >> 16));
            float g2f = bf2f((u16)(g2.y & 0xffff)), g3 = bf2f((u16)(g2.y >> 16));
            f32x4 o = Oacc[cf][nf];
            *(uint2*)&wavg[idx] = pack4(o[0] * rl * g0, o[1] * rl * g1,
                                        o[2] * rl * g2f, o[3] * rl * g3);
        }
    }
}

// ---------------------------------------------------------------------------
extern "C" void kernel_launch(void* const* d_in, const int* in_sizes, int n_in,
                              void* d_out, int out_size, void* d_ws, size_t ws_size,
                              hipStream_t stream) {
    const float* q_data = (const float*)d_in[0];
    const float* m_data = (const float*)d_in[1];
    const float* bias   = (const float*)d_in[2];
    const float* nbias  = (const float*)d_in[3];
    const float* q_w    = (const float*)d_in[4];
    const float* k_w    = (const float*)d_in[5];
    const float* v_w    = (const float*)d_in[6];
    const float* o_w    = (const float*)d_in[7];
    const float* o_b    = (const float*)d_in[8];
    const float* g_w    = (const float*)d_in[9];
    const float* g_b    = (const float*)d_in[10];
    float* out = (float*)d_out;

    const size_t MB = (size_t)NB * SQ * DM * 2;   // 25165824 bytes per bf16 buffer
    char* ws = (char*)d_ws;
    u16* qb    = (u16*)(ws);
    u16* kb    = (u16*)(ws + MB);
    u16* vTb   = (u16*)(ws + 2 * MB);
    u16* gateb = (u16*)(ws + 3 * MB);
    u16* wavg  = (u16*)(ws + 4 * MB);
    u16* wt    = (u16*)(ws + 5 * MB);             // 5 x 128KB
    u16* Wtq = wt, *Wtk = wt + 65536, *Wtv = wt + 2 * 65536,
       *Wtg = wt + 3 * 65536, *Wto = wt + 4 * 65536;

    prep_w<<<dim3(4, 4, 5), 256, 0, stream>>>(q_w, k_w, v_w, g_w, o_w, wt);
    proj_kernel<0><<<768, 256, 0, stream>>>(q_data, nullptr, Wtq, Wtg, g_b, nullptr,
                                            qb, gateb, nullptr, nullptr);
    proj_kernel<1><<<768, 256, 0, stream>>>(m_data, nullptr, Wtk, Wtv, nullptr, nullptr,
                                            kb, nullptr, vTb, nullptr);
    attn_kernel<<<dim3(768, 2), 256, 0, stream>>>(qb, kb, vTb, gateb, bias, nbias, wavg);
    proj_kernel<2><<<768, 256, 0, stream>>>(nullptr, wavg, Wto, nullptr, nullptr, o_b,
                                            nullptr, nullptr, nullptr, out);
}